// Round 1
// baseline (413.673 us; speedup 1.0000x reference)
//
#include <hip/hip_runtime.h>
#include <math.h>

#define GELU(v) (0.5f * (v) * (1.0f + erff((v)*0.70710678118654752440f)))

// ---------------- Kernel A: conv1 (1->16, 3x3 SAME) + maxpool2 + gelu ----------
// x:[32,1,256,256] -> h1:[32,16,128,128]
__global__ __launch_bounds__(256) void k_enc1(const float* __restrict__ x,
                                              const float* __restrict__ w,
                                              const float* __restrict__ bias,
                                              float* __restrict__ h1) {
  __shared__ float sw[144];
  __shared__ float sb[16];
  int tid = threadIdx.x;
  if (tid < 144) sw[tid] = w[tid];
  if (tid < 16) sb[tid] = bias[tid];
  __syncthreads();
  int gid = blockIdx.x * 256 + tid;            // over 32*128*128
  int xx = gid & 127, yy = (gid >> 7) & 127, b = gid >> 14;
  const float* xp = x + (size_t)b * 65536;
  int r0 = 2 * yy - 1, c0 = 2 * xx - 1;        // 4x4 input window
  float in[4][4];
#pragma unroll
  for (int i = 0; i < 4; ++i) {
    int r = r0 + i;
    bool rv = (unsigned)r < 256u;
#pragma unroll
    for (int j = 0; j < 4; ++j) {
      int c = c0 + j;
      in[i][j] = (rv && (unsigned)c < 256u) ? xp[r * 256 + c] : 0.0f;
    }
  }
  float* op = h1 + (size_t)b * 262144 + yy * 128 + xx;
#pragma unroll
  for (int oc = 0; oc < 16; ++oc) {
    float s00 = 0.f, s01 = 0.f, s10 = 0.f, s11 = 0.f;
#pragma unroll
    for (int ky = 0; ky < 3; ++ky)
#pragma unroll
      for (int kx = 0; kx < 3; ++kx) {
        float wv = sw[oc * 9 + ky * 3 + kx];
        s00 = fmaf(in[ky][kx], wv, s00);
        s01 = fmaf(in[ky][kx + 1], wv, s01);
        s10 = fmaf(in[ky + 1][kx], wv, s10);
        s11 = fmaf(in[ky + 1][kx + 1], wv, s11);
      }
    float bb = sb[oc];
    float m = fmaxf(fmaxf(s00 + bb, s01 + bb), fmaxf(s10 + bb, s11 + bb));
    op[oc * 16384] = GELU(m);
  }
}

// ---------------- Kernel B: conv2 (16->32, 3x3 SAME) + maxpool2 ----------------
// h1:[32,16,128,128] -> h2:[32,32,64,64]
// block 256 = 4 waves; wave = 8-oc group; 64 lanes = 8x8 pooled pixels;
// each thread: 2x2 pre-pool positions x 8 oc accumulated in registers.
__global__ __launch_bounds__(256) void k_enc2(const float* __restrict__ h1,
                                              const float* __restrict__ w,
                                              const float* __restrict__ bias,
                                              float* __restrict__ h2) {
  __shared__ float st[16 * 342];                 // 18x18 tile, row stride 19, x16 ic
  __shared__ __align__(16) float swt[144 * 32];  // transposed [ic*9+k][oc]
  __shared__ float sb[32];
  int tid = threadIdx.x;
  for (int i = tid; i < 4608; i += 256) {
    int oc = i / 144, r = i % 144;
    swt[r * 32 + oc] = w[i];
  }
  if (tid < 32) sb[tid] = bias[tid];
  int b = blockIdx.y;
  int Y0 = (blockIdx.x >> 3) * 8, X0 = (blockIdx.x & 7) * 8;  // pooled tile base
  int r0 = 2 * Y0 - 1, c0 = 2 * X0 - 1;
  const float* ip = h1 + (size_t)b * 262144;
  for (int i = tid; i < 16 * 324; i += 256) {
    int ic = i / 324, rr = (i % 324) / 18, cc = i % 18;
    int r = r0 + rr, c = c0 + cc;
    st[ic * 342 + rr * 19 + cc] =
        ((unsigned)r < 128u && (unsigned)c < 128u) ? ip[ic * 16384 + r * 128 + c] : 0.f;
  }
  __syncthreads();
  int lane = tid & 63;
  int oc0 = (tid >> 6) * 8;
  int ty = lane >> 3, tx = lane & 7;
  float acc0[8], acc1[8], acc2[8], acc3[8];
#pragma unroll
  for (int o = 0; o < 8; ++o) acc0[o] = acc1[o] = acc2[o] = acc3[o] = 0.f;
  int base = 2 * ty * 19 + 2 * tx;
#pragma unroll 1
  for (int ic = 0; ic < 16; ++ic) {
    const float* t = st + ic * 342 + base;
#pragma unroll
    for (int k = 0; k < 9; ++k) {
      int ky = k / 3, kx = k % 3;
      float i00 = t[ky * 19 + kx];
      float i01 = t[ky * 19 + kx + 1];
      float i10 = t[ky * 19 + kx + 19];
      float i11 = t[ky * 19 + kx + 20];
      const float4* wp = (const float4*)(swt + (ic * 9 + k) * 32 + oc0);
      float4 wa = wp[0], wb = wp[1];
      float w8[8] = {wa.x, wa.y, wa.z, wa.w, wb.x, wb.y, wb.z, wb.w};
#pragma unroll
      for (int o = 0; o < 8; ++o) {
        float wv = w8[o];
        acc0[o] = fmaf(i00, wv, acc0[o]);
        acc1[o] = fmaf(i01, wv, acc1[o]);
        acc2[o] = fmaf(i10, wv, acc2[o]);
        acc3[o] = fmaf(i11, wv, acc3[o]);
      }
    }
  }
  int oy = Y0 + ty, ox = X0 + tx;
  float* op = h2 + (size_t)b * 131072 + oy * 64 + ox;
#pragma unroll
  for (int o = 0; o < 8; ++o) {
    float bb = sb[oc0 + o];
    float m = fmaxf(fmaxf(acc0[o] + bb, acc1[o] + bb), fmaxf(acc2[o] + bb, acc3[o] + bb));
    op[(oc0 + o) * 4096] = m;
  }
}

// ---------------- Kernel C: vector quantize (in-place on h2) -------------------
// h2:[32,32,64,64] tokens (b,y,x) over channel dim. Codebook [512,32].
// 2 tokens/thread; codebook staged through LDS in two 32KB phases.
__global__ __launch_bounds__(256) void k_vq(float* __restrict__ h2,
                                            const float* __restrict__ cb,
                                            float* __restrict__ idxout,
                                            float* __restrict__ partial) {
  __shared__ __align__(16) float scb[8192];  // 256 codes x 32
  __shared__ float scsq[512];
  __shared__ float sred[4];
  int tid = threadIdx.x;
  for (int j = tid; j < 512; j += 256) {
    float s = 0.f;
#pragma unroll
    for (int d = 0; d < 32; ++d) {
      float v = cb[j * 32 + d];
      s = fmaf(v, v, s);
    }
    scsq[j] = s;
  }
  int gid = blockIdx.x * 256 + tid;  // 0..65535
  int t0 = gid, t1 = gid + 65536;
  size_t a0 = (size_t)(t0 >> 12) * 131072 + (t0 & 4095);
  size_t a1 = (size_t)(t1 >> 12) * 131072 + (t1 & 4095);
  float f0[32], f1[32];
#pragma unroll
  for (int c = 0; c < 32; ++c) {
    f0[c] = h2[a0 + c * 4096];
    f1[c] = h2[a1 + c * 4096];
  }
  float best0 = 3.4e38f, best1 = 3.4e38f;
  int bi0 = 0, bi1 = 0;
  const float4* cbg4 = (const float4*)cb;
  float4* scb4 = (float4*)scb;
  for (int ph = 0; ph < 2; ++ph) {
    __syncthreads();
    for (int i = tid; i < 2048; i += 256) scb4[i] = cbg4[ph * 2048 + i];
    __syncthreads();
    int jbase = ph * 256;
    for (int jl = 0; jl < 256; ++jl) {
      const float4* row = scb4 + (jl << 3);
      float a0s = 0.f, b0s = 0.f, a1s = 0.f, b1s = 0.f;
#pragma unroll
      for (int q = 0; q < 8; q += 2) {
        float4 v = row[q], u = row[q + 1];
        a0s = fmaf(v.x, f0[4*q+0], a0s); a0s = fmaf(v.y, f0[4*q+1], a0s);
        a0s = fmaf(v.z, f0[4*q+2], a0s); a0s = fmaf(v.w, f0[4*q+3], a0s);
        b0s = fmaf(u.x, f0[4*q+4], b0s); b0s = fmaf(u.y, f0[4*q+5], b0s);
        b0s = fmaf(u.z, f0[4*q+6], b0s); b0s = fmaf(u.w, f0[4*q+7], b0s);
        a1s = fmaf(v.x, f1[4*q+0], a1s); a1s = fmaf(v.y, f1[4*q+1], a1s);
        a1s = fmaf(v.z, f1[4*q+2], a1s); a1s = fmaf(v.w, f1[4*q+3], a1s);
        b1s = fmaf(u.x, f1[4*q+4], b1s); b1s = fmaf(u.y, f1[4*q+5], b1s);
        b1s = fmaf(u.z, f1[4*q+6], b1s); b1s = fmaf(u.w, f1[4*q+7], b1s);
      }
      float csq = scsq[jbase + jl];
      float d0 = csq - 2.0f * (a0s + b0s);
      float d1 = csq - 2.0f * (a1s + b1s);
      if (d0 < best0) { best0 = d0; bi0 = jbase + jl; }  // strict <: first-min, matches argmin
      if (d1 < best1) { best1 = d1; bi1 = jbase + jl; }
    }
  }
  float loss = 0.f;
  const float* q0 = cb + bi0 * 32;
  const float* q1 = cb + bi1 * 32;
#pragma unroll
  for (int c = 0; c < 32; ++c) {
    float qv = q0[c];
    h2[a0 + c * 4096] = qv;
    float d = qv - f0[c];
    loss = fmaf(d, d, loss);
  }
#pragma unroll
  for (int c = 0; c < 32; ++c) {
    float qv = q1[c];
    h2[a1 + c * 4096] = qv;
    float d = qv - f1[c];
    loss = fmaf(d, d, loss);
  }
  idxout[t0] = (float)bi0;
  idxout[t1] = (float)bi1;
#pragma unroll
  for (int off = 32; off > 0; off >>= 1) loss += __shfl_down(loss, off, 64);
  if ((tid & 63) == 0) sred[tid >> 6] = loss;
  __syncthreads();
  if (tid == 0) partial[blockIdx.x] = (sred[0] + sred[1]) + (sred[2] + sred[3]);
}

// ---------------- Kernel F: finalize commit loss -------------------------------
__global__ __launch_bounds__(256) void k_loss(const float* __restrict__ partial,
                                              float* __restrict__ lossout) {
  __shared__ float sred[4];
  float v = partial[threadIdx.x];
#pragma unroll
  for (int off = 32; off > 0; off >>= 1) v += __shfl_down(v, off, 64);
  if ((threadIdx.x & 63) == 0) sred[threadIdx.x >> 6] = v;
  __syncthreads();
  if (threadIdx.x == 0)
    lossout[0] = ((sred[0] + sred[1]) + (sred[2] + sred[3])) * (1.0f / 4194304.0f);
}

// ---------------- Kernel D: up2 + conv (32->16, 3x3 SAME) + gelu ---------------
// q:[32,32,64,64] -> o:[32,16,128,128]. Zero-padded 10x10 q-tile in LDS; inner
// loop uses >>1 index mapping (no guards: (-1)>>1=-1 lands in padded border).
__global__ __launch_bounds__(128) void k_dec1(const float* __restrict__ q,
                                              const float* __restrict__ w,
                                              const float* __restrict__ bias,
                                              float* __restrict__ o) {
  __shared__ float st[3200];                     // [32 ic][10*10]
  __shared__ __align__(16) float swt[288 * 16];  // [ic*9+k][oc]
  __shared__ float sb[16];
  int tid = threadIdx.x;
  for (int i = tid; i < 4608; i += 128) {
    int oc = i / 288, r = i % 288;
    swt[r * 16 + oc] = w[i];
  }
  if (tid < 16) sb[tid] = bias[tid];
  int b = blockIdx.y;
  int Y0 = (blockIdx.x >> 3) * 16, X0 = (blockIdx.x & 7) * 16;
  int m = Y0 >> 1, n = X0 >> 1;  // q tile rows m-1..m+8
  const float* ip = q + (size_t)b * 131072;
  for (int i = tid; i < 3200; i += 128) {
    int ic = i / 100, rr = (i % 100) / 10, cc = i % 10;
    int r = m - 1 + rr, c = n - 1 + cc;
    st[i] = ((unsigned)r < 64u && (unsigned)c < 64u) ? ip[ic * 4096 + r * 64 + c] : 0.f;
  }
  __syncthreads();
  int lane = tid & 63, oc0 = (tid >> 6) * 8;
  int ty = lane >> 3, tx = lane & 7;
  int Y = Y0 + 2 * ty, X = X0 + 2 * tx;
  float acc0[8], acc1[8], acc2[8], acc3[8];
#pragma unroll
  for (int o2 = 0; o2 < 8; ++o2) acc0[o2] = acc1[o2] = acc2[o2] = acc3[o2] = 0.f;
#pragma unroll 1
  for (int ic = 0; ic < 32; ++ic) {
    const float* t = st + ic * 100;
#pragma unroll
    for (int k = 0; k < 9; ++k) {
      int ky = k / 3, kx = k % 3;
      int rA = ((Y + ky - 1) >> 1) - (m - 1);
      int rB = ((Y + ky) >> 1) - (m - 1);
      int cA = ((X + kx - 1) >> 1) - (n - 1);
      int cB = ((X + kx) >> 1) - (n - 1);
      float i00 = t[rA * 10 + cA], i01 = t[rA * 10 + cB];
      float i10 = t[rB * 10 + cA], i11 = t[rB * 10 + cB];
      const float4* wp = (const float4*)(swt + (ic * 9 + k) * 16 + oc0);
      float4 wa = wp[0], wb = wp[1];
      float w8[8] = {wa.x, wa.y, wa.z, wa.w, wb.x, wb.y, wb.z, wb.w};
#pragma unroll
      for (int o2 = 0; o2 < 8; ++o2) {
        float wv = w8[o2];
        acc0[o2] = fmaf(i00, wv, acc0[o2]);
        acc1[o2] = fmaf(i01, wv, acc1[o2]);
        acc2[o2] = fmaf(i10, wv, acc2[o2]);
        acc3[o2] = fmaf(i11, wv, acc3[o2]);
      }
    }
  }
  float* op = o + (size_t)b * 262144 + Y * 128 + X;
#pragma unroll
  for (int o2 = 0; o2 < 8; ++o2) {
    float bb = sb[oc0 + o2];
    float v00 = GELU(acc0[o2] + bb);
    float v01 = GELU(acc1[o2] + bb);
    float v10 = GELU(acc2[o2] + bb);
    float v11 = GELU(acc3[o2] + bb);
    float* p = op + (size_t)(oc0 + o2) * 16384;
    p[0] = v00; p[1] = v01; p[128] = v10; p[129] = v11;
  }
}

// ---------------- Kernel E: up2 + conv (16->1, 3x3 SAME) + clip ----------------
// d1:[32,16,128,128] -> out:[32,1,256,256]. Thread computes 4x4 output pixels.
__global__ __launch_bounds__(64) void k_dec2(const float* __restrict__ d1,
                                             const float* __restrict__ w,
                                             const float* __restrict__ bias,
                                             float* __restrict__ out) {
  __shared__ float st[16 * 324];  // 18x18 zero-padded d1 tile x16 ic
  __shared__ float sw[144];
  int tid = threadIdx.x;
  for (int i = tid; i < 144; i += 64) sw[i] = w[i];
  int b = blockIdx.y;
  int Y0 = (blockIdx.x >> 3) * 32, X0 = (blockIdx.x & 7) * 32;
  int m = Y0 >> 1, n = X0 >> 1;  // d1 tile rows m-1..m+16
  const float* ip = d1 + (size_t)b * 262144;
  for (int i = tid; i < 5184; i += 64) {
    int ic = i / 324, rr = (i % 324) / 18, cc = i % 18;
    int r = m - 1 + rr, c = n - 1 + cc;
    st[i] = ((unsigned)r < 128u && (unsigned)c < 128u) ? ip[ic * 16384 + r * 128 + c] : 0.f;
  }
  __syncthreads();
  float bv = bias[0];
  int ty = tid >> 3, tx = tid & 7;
  int Y = Y0 + 4 * ty, X = X0 + 4 * tx;
  float acc[4][4];
#pragma unroll
  for (int py = 0; py < 4; ++py)
#pragma unroll
    for (int px = 0; px < 4; ++px) acc[py][px] = 0.f;
  int lbase = (2 * ty) * 18 + 2 * tx;
#pragma unroll 1
  for (int ic = 0; ic < 16; ++ic) {
    const float* t = st + ic * 324 + lbase;
    float dv[4][4];
#pragma unroll
    for (int r = 0; r < 4; ++r)
#pragma unroll
      for (int c = 0; c < 4; ++c) dv[r][c] = t[r * 18 + c];
#pragma unroll
    for (int ky = 0; ky < 3; ++ky)
#pragma unroll
      for (int kx = 0; kx < 3; ++kx) {
        float wv = sw[ic * 9 + ky * 3 + kx];
#pragma unroll
        for (int py = 0; py < 4; ++py)
#pragma unroll
          for (int px = 0; px < 4; ++px) {
            float iv = dv[(py + ky + 1) >> 1][(px + kx + 1) >> 1];
            acc[py][px] = fmaf(iv, wv, acc[py][px]);
          }
      }
  }
  float* op = out + (size_t)b * 65536 + Y * 256 + X;
#pragma unroll
  for (int py = 0; py < 4; ++py) {
    float4 v;
    v.x = fminf(1.0f, fmaxf(-1.0f, acc[py][0] + bv));
    v.y = fminf(1.0f, fmaxf(-1.0f, acc[py][1] + bv));
    v.z = fminf(1.0f, fmaxf(-1.0f, acc[py][2] + bv));
    v.w = fminf(1.0f, fmaxf(-1.0f, acc[py][3] + bv));
    *(float4*)(op + py * 256) = v;
  }
}

extern "C" void kernel_launch(void* const* d_in, const int* in_sizes, int n_in,
                              void* d_out, int out_size, void* d_ws, size_t ws_size,
                              hipStream_t stream) {
  const float* x   = (const float*)d_in[0];
  const float* e1w = (const float*)d_in[1];
  const float* e1b = (const float*)d_in[2];
  const float* e2w = (const float*)d_in[3];
  const float* e2b = (const float*)d_in[4];
  const float* cb  = (const float*)d_in[5];
  const float* d1w = (const float*)d_in[6];
  const float* d1b = (const float*)d_in[7];
  const float* d2w = (const float*)d_in[8];
  const float* d2b = (const float*)d_in[9];

  float* out = (float*)d_out;
  float* y       = out;                       // [32,1,256,256] = 2097152
  float* idxout  = out + 2097152;             // [32,64,64]     = 131072 (as float)
  float* lossout = out + 2097152 + 131072;    // scalar

  float* ws = (float*)d_ws;
  float* h1      = ws;                        // [32,16,128,128] = 8388608 floats
  float* h2      = ws + 8388608;              // [32,32,64,64]   = 4194304 floats (q in-place)
  float* partial = ws + 8388608 + 4194304;    // 256 floats
  float* d1o     = h1;                        // reuse h1 (dead after k_enc2)

  k_enc1<<<dim3(2048), 256, 0, stream>>>(x, e1w, e1b, h1);
  k_enc2<<<dim3(64, 32), 256, 0, stream>>>(h1, e2w, e2b, h2);
  k_vq<<<dim3(256), 256, 0, stream>>>(h2, cb, idxout, partial);
  k_loss<<<dim3(1), 256, 0, stream>>>(partial, lossout);
  k_dec1<<<dim3(64, 32), 128, 0, stream>>>(h2, d1w, d1b, d1o);
  k_dec2<<<dim3(64, 32), 64, 0, stream>>>(d1o, d2w, d2b, y);
}

// Round 2
// 368.395 us; speedup vs baseline: 1.1229x; 1.1229x over previous
//
#include <hip/hip_runtime.h>
#include <math.h>

#define GELU(v) (0.5f * (v) * (1.0f + erff((v)*0.70710678118654752440f)))

// ---------------- Kernel A: conv1 (1->16, 3x3 SAME) + maxpool2 + gelu ----------
// x:[32,1,256,256] -> h1:[32,16,128,128]
__global__ __launch_bounds__(256) void k_enc1(const float* __restrict__ x,
                                              const float* __restrict__ w,
                                              const float* __restrict__ bias,
                                              float* __restrict__ h1) {
  __shared__ float sw[144];
  __shared__ float sb[16];
  int tid = threadIdx.x;
  if (tid < 144) sw[tid] = w[tid];
  if (tid < 16) sb[tid] = bias[tid];
  __syncthreads();
  int gid = blockIdx.x * 256 + tid;            // over 32*128*128
  int xx = gid & 127, yy = (gid >> 7) & 127, b = gid >> 14;
  const float* xp = x + (size_t)b * 65536;
  int r0 = 2 * yy - 1, c0 = 2 * xx - 1;        // 4x4 input window
  float in[4][4];
#pragma unroll
  for (int i = 0; i < 4; ++i) {
    int r = r0 + i;
    bool rv = (unsigned)r < 256u;
#pragma unroll
    for (int j = 0; j < 4; ++j) {
      int c = c0 + j;
      in[i][j] = (rv && (unsigned)c < 256u) ? xp[r * 256 + c] : 0.0f;
    }
  }
  float* op = h1 + (size_t)b * 262144 + yy * 128 + xx;
#pragma unroll
  for (int oc = 0; oc < 16; ++oc) {
    float s00 = 0.f, s01 = 0.f, s10 = 0.f, s11 = 0.f;
#pragma unroll
    for (int ky = 0; ky < 3; ++ky)
#pragma unroll
      for (int kx = 0; kx < 3; ++kx) {
        float wv = sw[oc * 9 + ky * 3 + kx];
        s00 = fmaf(in[ky][kx], wv, s00);
        s01 = fmaf(in[ky][kx + 1], wv, s01);
        s10 = fmaf(in[ky + 1][kx], wv, s10);
        s11 = fmaf(in[ky + 1][kx + 1], wv, s11);
      }
    float bb = sb[oc];
    float m = fmaxf(fmaxf(s00 + bb, s01 + bb), fmaxf(s10 + bb, s11 + bb));
    op[oc * 16384] = GELU(m);
  }
}

// ---------------- Kernel B: conv2 (16->32, 3x3 SAME) + maxpool2 ----------------
// h1:[32,16,128,128] -> h2:[32,32,64,64]
__global__ __launch_bounds__(256) void k_enc2(const float* __restrict__ h1,
                                              const float* __restrict__ w,
                                              const float* __restrict__ bias,
                                              float* __restrict__ h2) {
  __shared__ float st[16 * 342];                 // 18x18 tile, row stride 19, x16 ic
  __shared__ __align__(16) float swt[144 * 32];  // transposed [ic*9+k][oc]
  __shared__ float sb[32];
  int tid = threadIdx.x;
  for (int i = tid; i < 4608; i += 256) {
    int oc = i / 144, r = i % 144;
    swt[r * 32 + oc] = w[i];
  }
  if (tid < 32) sb[tid] = bias[tid];
  int b = blockIdx.y;
  int Y0 = (blockIdx.x >> 3) * 8, X0 = (blockIdx.x & 7) * 8;  // pooled tile base
  int r0 = 2 * Y0 - 1, c0 = 2 * X0 - 1;
  const float* ip = h1 + (size_t)b * 262144;
  for (int i = tid; i < 16 * 324; i += 256) {
    int ic = i / 324, rr = (i % 324) / 18, cc = i % 18;
    int r = r0 + rr, c = c0 + cc;
    st[ic * 342 + rr * 19 + cc] =
        ((unsigned)r < 128u && (unsigned)c < 128u) ? ip[ic * 16384 + r * 128 + c] : 0.f;
  }
  __syncthreads();
  int lane = tid & 63;
  int oc0 = (tid >> 6) * 8;
  int ty = lane >> 3, tx = lane & 7;
  float acc0[8], acc1[8], acc2[8], acc3[8];
#pragma unroll
  for (int o = 0; o < 8; ++o) acc0[o] = acc1[o] = acc2[o] = acc3[o] = 0.f;
  int base = 2 * ty * 19 + 2 * tx;
#pragma unroll 1
  for (int ic = 0; ic < 16; ++ic) {
    const float* t = st + ic * 342 + base;
#pragma unroll
    for (int k = 0; k < 9; ++k) {
      int ky = k / 3, kx = k % 3;
      float i00 = t[ky * 19 + kx];
      float i01 = t[ky * 19 + kx + 1];
      float i10 = t[ky * 19 + kx + 19];
      float i11 = t[ky * 19 + kx + 20];
      const float4* wp = (const float4*)(swt + (ic * 9 + k) * 32 + oc0);
      float4 wa = wp[0], wb = wp[1];
      float w8[8] = {wa.x, wa.y, wa.z, wa.w, wb.x, wb.y, wb.z, wb.w};
#pragma unroll
      for (int o = 0; o < 8; ++o) {
        float wv = w8[o];
        acc0[o] = fmaf(i00, wv, acc0[o]);
        acc1[o] = fmaf(i01, wv, acc1[o]);
        acc2[o] = fmaf(i10, wv, acc2[o]);
        acc3[o] = fmaf(i11, wv, acc3[o]);
      }
    }
  }
  int oy = Y0 + ty, ox = X0 + tx;
  float* op = h2 + (size_t)b * 131072 + oy * 64 + ox;
#pragma unroll
  for (int o = 0; o < 8; ++o) {
    float bb = sb[oc0 + o];
    float m = fmaxf(fmaxf(acc0[o] + bb, acc1[o] + bb), fmaxf(acc2[o] + bb, acc3[o] + bb));
    op[(oc0 + o) * 4096] = m;
  }
}

// ---------------- Kernel C1: VQ distance scan over a 128-code chunk ------------
// 4-way codebook split for occupancy: 1024 blocks (4 chunks x 256 token-blocks),
// 2 tokens/thread, 4 blocks/CU -> 16 waves/CU. Codebook rows read directly from
// global (wave-uniform address -> L1-resident 16KB chunk / scalarizable).
__global__ __launch_bounds__(256) void k_vq_chunk(const float* __restrict__ h2,
                                                  const float* __restrict__ cb,
                                                  float* __restrict__ dists,
                                                  int* __restrict__ idxs) {
  __shared__ float scsq[128];
  int tid = threadIdx.x;
  int chunk = blockIdx.x >> 8;        // 0..3
  int jbase = chunk << 7;             // 128-code chunk base
  if (tid < 128) {
    const float* row = cb + (size_t)(jbase + tid) * 32;
    float s = 0.f;
#pragma unroll
    for (int d = 0; d < 32; ++d) s = fmaf(row[d], row[d], s);
    scsq[tid] = s;
  }
  __syncthreads();
  int gid = (blockIdx.x & 255) * 256 + tid;  // 0..65535
  int t0 = gid, t1 = gid + 65536;
  size_t a0 = (size_t)(t0 >> 12) * 131072 + (t0 & 4095);
  size_t a1 = (size_t)(t1 >> 12) * 131072 + (t1 & 4095);
  float f0[32], f1[32];
#pragma unroll
  for (int c = 0; c < 32; ++c) {
    f0[c] = h2[a0 + c * 4096];
    f1[c] = h2[a1 + c * 4096];
  }
  float best0 = 3.4e38f, best1 = 3.4e38f;
  int bi0 = jbase, bi1 = jbase;
  const float4* r4 = (const float4*)(cb + (size_t)jbase * 32);
#pragma unroll 1
  for (int jl = 0; jl < 128; ++jl) {
    const float4* row = r4 + (jl << 3);
    float a0s = 0.f, b0s = 0.f, a1s = 0.f, b1s = 0.f;
#pragma unroll
    for (int q = 0; q < 8; q += 2) {
      float4 v = row[q], u = row[q + 1];
      a0s = fmaf(v.x, f0[4*q+0], a0s); a0s = fmaf(v.y, f0[4*q+1], a0s);
      a0s = fmaf(v.z, f0[4*q+2], a0s); a0s = fmaf(v.w, f0[4*q+3], a0s);
      b0s = fmaf(u.x, f0[4*q+4], b0s); b0s = fmaf(u.y, f0[4*q+5], b0s);
      b0s = fmaf(u.z, f0[4*q+6], b0s); b0s = fmaf(u.w, f0[4*q+7], b0s);
      a1s = fmaf(v.x, f1[4*q+0], a1s); a1s = fmaf(v.y, f1[4*q+1], a1s);
      a1s = fmaf(v.z, f1[4*q+2], a1s); a1s = fmaf(v.w, f1[4*q+3], a1s);
      b1s = fmaf(u.x, f1[4*q+4], b1s); b1s = fmaf(u.y, f1[4*q+5], b1s);
      b1s = fmaf(u.z, f1[4*q+6], b1s); b1s = fmaf(u.w, f1[4*q+7], b1s);
    }
    float csq = scsq[jl];
    float d0 = csq - 2.0f * (a0s + b0s);
    float d1 = csq - 2.0f * (a1s + b1s);
    if (d0 < best0) { best0 = d0; bi0 = jbase + jl; }  // strict <: first-min in chunk
    if (d1 < best1) { best1 = d1; bi1 = jbase + jl; }
  }
  size_t cbase = (size_t)chunk * 131072;
  dists[cbase + t0] = best0;
  dists[cbase + t1] = best1;
  idxs[cbase + t0] = bi0;
  idxs[cbase + t1] = bi1;
}

// ---------------- Kernel C2: merge 4 chunk candidates, quantize, loss ----------
__global__ __launch_bounds__(256) void k_vq_merge(float* __restrict__ h2,
                                                  const float* __restrict__ cb,
                                                  const float* __restrict__ dists,
                                                  const int* __restrict__ idxs,
                                                  float* __restrict__ idxout,
                                                  float* __restrict__ partial) {
  __shared__ float sred[4];
  int tid = threadIdx.x;
  int t = blockIdx.x * 256 + tid;
  float bd = dists[t];
  int bi = idxs[t];
#pragma unroll
  for (int k = 1; k < 4; ++k) {               // ascending chunk order: ties -> lowest idx
    float dk = dists[(size_t)k * 131072 + t];
    int ik = idxs[(size_t)k * 131072 + t];
    if (dk < bd) { bd = dk; bi = ik; }
  }
  size_t a = (size_t)(t >> 12) * 131072 + (t & 4095);
  const float* q = cb + (size_t)bi * 32;
  float loss = 0.f;
#pragma unroll
  for (int c = 0; c < 32; ++c) {
    float f = h2[a + c * 4096];
    float qv = q[c];
    h2[a + c * 4096] = qv;
    float dd = qv - f;
    loss = fmaf(dd, dd, loss);
  }
  idxout[t] = (float)bi;
#pragma unroll
  for (int off = 32; off > 0; off >>= 1) loss += __shfl_down(loss, off, 64);
  if ((tid & 63) == 0) sred[tid >> 6] = loss;
  __syncthreads();
  if (tid == 0) partial[blockIdx.x] = (sred[0] + sred[1]) + (sred[2] + sred[3]);
}

// ---------------- Kernel F: finalize commit loss (512 partials) ----------------
__global__ __launch_bounds__(256) void k_loss(const float* __restrict__ partial,
                                              float* __restrict__ lossout) {
  __shared__ float sred[4];
  int tid = threadIdx.x;
  float v = partial[tid] + partial[tid + 256];
#pragma unroll
  for (int off = 32; off > 0; off >>= 1) v += __shfl_down(v, off, 64);
  if ((tid & 63) == 0) sred[tid >> 6] = v;
  __syncthreads();
  if (tid == 0)
    lossout[0] = ((sred[0] + sred[1]) + (sred[2] + sred[3])) * (1.0f / 4194304.0f);
}

// ---------------- Kernel D: up2 + conv (32->16, 3x3 SAME) + gelu ---------------
// q:[32,32,64,64] -> o:[32,16,128,128]
__global__ __launch_bounds__(128) void k_dec1(const float* __restrict__ q,
                                              const float* __restrict__ w,
                                              const float* __restrict__ bias,
                                              float* __restrict__ o) {
  __shared__ float st[3200];                     // [32 ic][10*10]
  __shared__ __align__(16) float swt[288 * 16];  // [ic*9+k][oc]
  __shared__ float sb[16];
  int tid = threadIdx.x;
  for (int i = tid; i < 4608; i += 128) {
    int oc = i / 288, r = i % 288;
    swt[r * 16 + oc] = w[i];
  }
  if (tid < 16) sb[tid] = bias[tid];
  int b = blockIdx.y;
  int Y0 = (blockIdx.x >> 3) * 16, X0 = (blockIdx.x & 7) * 16;
  int m = Y0 >> 1, n = X0 >> 1;  // q tile rows m-1..m+8
  const float* ip = q + (size_t)b * 131072;
  for (int i = tid; i < 3200; i += 128) {
    int ic = i / 100, rr = (i % 100) / 10, cc = i % 10;
    int r = m - 1 + rr, c = n - 1 + cc;
    st[i] = ((unsigned)r < 64u && (unsigned)c < 64u) ? ip[ic * 4096 + r * 64 + c] : 0.f;
  }
  __syncthreads();
  int lane = tid & 63, oc0 = (tid >> 6) * 8;
  int ty = lane >> 3, tx = lane & 7;
  int Y = Y0 + 2 * ty, X = X0 + 2 * tx;
  float acc0[8], acc1[8], acc2[8], acc3[8];
#pragma unroll
  for (int o2 = 0; o2 < 8; ++o2) acc0[o2] = acc1[o2] = acc2[o2] = acc3[o2] = 0.f;
#pragma unroll 1
  for (int ic = 0; ic < 32; ++ic) {
    const float* t = st + ic * 100;
#pragma unroll
    for (int k = 0; k < 9; ++k) {
      int ky = k / 3, kx = k % 3;
      int rA = ((Y + ky - 1) >> 1) - (m - 1);
      int rB = ((Y + ky) >> 1) - (m - 1);
      int cA = ((X + kx - 1) >> 1) - (n - 1);
      int cB = ((X + kx) >> 1) - (n - 1);
      float i00 = t[rA * 10 + cA], i01 = t[rA * 10 + cB];
      float i10 = t[rB * 10 + cA], i11 = t[rB * 10 + cB];
      const float4* wp = (const float4*)(swt + (ic * 9 + k) * 16 + oc0);
      float4 wa = wp[0], wb = wp[1];
      float w8[8] = {wa.x, wa.y, wa.z, wa.w, wb.x, wb.y, wb.z, wb.w};
#pragma unroll
      for (int o2 = 0; o2 < 8; ++o2) {
        float wv = w8[o2];
        acc0[o2] = fmaf(i00, wv, acc0[o2]);
        acc1[o2] = fmaf(i01, wv, acc1[o2]);
        acc2[o2] = fmaf(i10, wv, acc2[o2]);
        acc3[o2] = fmaf(i11, wv, acc3[o2]);
      }
    }
  }
  float* op = o + (size_t)b * 262144 + Y * 128 + X;
#pragma unroll
  for (int o2 = 0; o2 < 8; ++o2) {
    float bb = sb[oc0 + o2];
    float v00 = GELU(acc0[o2] + bb);
    float v01 = GELU(acc1[o2] + bb);
    float v10 = GELU(acc2[o2] + bb);
    float v11 = GELU(acc3[o2] + bb);
    float* p = op + (size_t)(oc0 + o2) * 16384;
    p[0] = v00; p[1] = v01; p[128] = v10; p[129] = v11;
  }
}

// ---------------- Kernel E: up2 + conv (16->1, 3x3 SAME) + clip ----------------
// d1:[32,16,128,128] -> out:[32,1,256,256]. 128 thr/block (2 waves), thread does
// 2 rows x 4 cols. Same 21.3KB LDS tile -> ~14 waves/CU (was 7 at 64 thr).
__global__ __launch_bounds__(128) void k_dec2(const float* __restrict__ d1,
                                              const float* __restrict__ w,
                                              const float* __restrict__ bias,
                                              float* __restrict__ out) {
  __shared__ float st[16 * 324];  // 18x18 zero-padded d1 tile x16 ic
  __shared__ float sw[144];
  int tid = threadIdx.x;
  for (int i = tid; i < 144; i += 128) sw[i] = w[i];
  int b = blockIdx.y;
  int Y0 = (blockIdx.x >> 3) * 32, X0 = (blockIdx.x & 7) * 32;
  int m = Y0 >> 1, n = X0 >> 1;  // d1 tile rows m-1..m+16
  const float* ip = d1 + (size_t)b * 262144;
  for (int i = tid; i < 5184; i += 128) {
    int ic = i / 324, rr = (i % 324) / 18, cc = i % 18;
    int r = m - 1 + rr, c = n - 1 + cc;
    st[i] = ((unsigned)r < 128u && (unsigned)c < 128u) ? ip[ic * 16384 + r * 128 + c] : 0.f;
  }
  __syncthreads();
  float bv = bias[0];
  int ty = tid >> 3, tx = tid & 7;          // ty 0..15, tx 0..7
  int Y = Y0 + 2 * ty, X = X0 + 4 * tx;
  float acc[2][4];
#pragma unroll
  for (int py = 0; py < 2; ++py)
#pragma unroll
    for (int px = 0; px < 4; ++px) acc[py][px] = 0.f;
  int lbase = ty * 18 + 2 * tx;
#pragma unroll 1
  for (int ic = 0; ic < 16; ++ic) {
    const float* t = st + ic * 324 + lbase;
    float dv[3][4];
#pragma unroll
    for (int r = 0; r < 3; ++r)
#pragma unroll
      for (int c = 0; c < 4; ++c) dv[r][c] = t[r * 18 + c];
#pragma unroll
    for (int ky = 0; ky < 3; ++ky)
#pragma unroll
      for (int kx = 0; kx < 3; ++kx) {
        float wv = sw[ic * 9 + ky * 3 + kx];
#pragma unroll
        for (int py = 0; py < 2; ++py)
#pragma unroll
          for (int px = 0; px < 4; ++px) {
            float iv = dv[(py + ky + 1) >> 1][(px + kx + 1) >> 1];
            acc[py][px] = fmaf(iv, wv, acc[py][px]);
          }
      }
  }
  float* op = out + (size_t)b * 65536 + Y * 256 + X;
#pragma unroll
  for (int py = 0; py < 2; ++py) {
    float4 v;
    v.x = fminf(1.0f, fmaxf(-1.0f, acc[py][0] + bv));
    v.y = fminf(1.0f, fmaxf(-1.0f, acc[py][1] + bv));
    v.z = fminf(1.0f, fmaxf(-1.0f, acc[py][2] + bv));
    v.w = fminf(1.0f, fmaxf(-1.0f, acc[py][3] + bv));
    *(float4*)(op + py * 256) = v;
  }
}

extern "C" void kernel_launch(void* const* d_in, const int* in_sizes, int n_in,
                              void* d_out, int out_size, void* d_ws, size_t ws_size,
                              hipStream_t stream) {
  const float* x   = (const float*)d_in[0];
  const float* e1w = (const float*)d_in[1];
  const float* e1b = (const float*)d_in[2];
  const float* e2w = (const float*)d_in[3];
  const float* e2b = (const float*)d_in[4];
  const float* cb  = (const float*)d_in[5];
  const float* d1w = (const float*)d_in[6];
  const float* d1b = (const float*)d_in[7];
  const float* d2w = (const float*)d_in[8];
  const float* d2b = (const float*)d_in[9];

  float* out = (float*)d_out;
  float* y       = out;                       // [32,1,256,256] = 2097152
  float* idxout  = out + 2097152;             // [32,64,64]     = 131072 (as float)
  float* lossout = out + 2097152 + 131072;    // scalar

  float* ws = (float*)d_ws;
  float* h1      = ws;                        // [32,16,128,128] = 8388608 floats
  float* h2      = ws + 8388608;              // [32,32,64,64]   = 4194304 floats (q in-place)
  float* partial = ws + 8388608 + 4194304;    // 512 floats
  // VQ chunk outputs reuse the (dead-after-enc2) h1 region:
  float* dists   = ws;                        // 4 x 131072 floats
  int*   idxs    = (int*)(ws + 524288);       // 4 x 131072 ints
  float* d1o     = h1;                        // dec1 output reuses h1 (after merge)

  k_enc1<<<dim3(2048), 256, 0, stream>>>(x, e1w, e1b, h1);
  k_enc2<<<dim3(64, 32), 256, 0, stream>>>(h1, e2w, e2b, h2);
  k_vq_chunk<<<dim3(1024), 256, 0, stream>>>(h2, cb, dists, idxs);
  k_vq_merge<<<dim3(512), 256, 0, stream>>>(h2, cb, dists, idxs, idxout, partial);
  k_loss<<<dim3(1), 256, 0, stream>>>(partial, lossout);
  k_dec1<<<dim3(64, 32), 128, 0, stream>>>(h2, d1w, d1b, d1o);
  k_dec2<<<dim3(64, 32), 128, 0, stream>>>(d1o, d2w, d2b, y);
}

// Round 3
// 299.143 us; speedup vs baseline: 1.3829x; 1.2315x over previous
//
#include <hip/hip_runtime.h>
#include <math.h>

#define GELU(v) (0.5f * (v) * (1.0f + erff((v)*0.70710678118654752440f)))

// ---------------- Setup: fold/transpose weights --------------------------------
// fwe2[grp(4)][ic(16)][k(9)][o(8)]            : enc2 transposed    (4608)
// fwd1[grp(2)][ic(32)][phase(4)][tap(4)][o(8)]: dec1 up2-folded    (8192)
// fwd2[ic(16)][phase(4)][tap(4)]              : dec2 up2-folded    (256)
// Fold rule (nearest-up2 then 3x3): phase a rows -> a=0:{ky0->dy0, ky1,ky2->dy1},
// a=1:{ky0,ky1->dy0, ky2->dy1}; same for columns with b.
__global__ __launch_bounds__(256) void k_fold(const float* __restrict__ e2w,
                                              const float* __restrict__ d1w,
                                              const float* __restrict__ d2w,
                                              float* __restrict__ fwe2,
                                              float* __restrict__ fwd1,
                                              float* __restrict__ fwd2) {
  int i = blockIdx.x * 256 + threadIdx.x;
  if (i < 4608) {
    int o = i & 7, k = (i >> 3) % 9, ic = (i / 72) & 15, grp = i / 1152;
    fwe2[i] = e2w[((grp * 8 + o) * 16 + ic) * 9 + k];
  } else if (i < 12800) {
    int j = i - 4608;
    int o = j & 7, pt = (j >> 3) & 15, ic = (j >> 7) & 31, grp = j >> 12;
    int a = pt >> 3, b2 = (pt >> 2) & 1, dy = (pt >> 1) & 1, dx = pt & 1;
    const float* wsrc = d1w + ((grp * 8 + o) * 32 + ic) * 9;
    float s = 0.f;
    for (int ky = 0; ky < 3; ++ky) {
      int rm = (a == 0) ? (ky == 0 ? 0 : 1) : (ky == 2 ? 1 : 0);
      if (rm != dy) continue;
      for (int kx = 0; kx < 3; ++kx) {
        int cm = (b2 == 0) ? (kx == 0 ? 0 : 1) : (kx == 2 ? 1 : 0);
        if (cm == dx) s += wsrc[ky * 3 + kx];
      }
    }
    fwd1[j] = s;
  } else if (i < 13056) {
    int j = i - 12800;
    int pt = j & 15, ic = j >> 4;
    int a = pt >> 3, b2 = (pt >> 2) & 1, dy = (pt >> 1) & 1, dx = pt & 1;
    const float* wsrc = d2w + ic * 9;
    float s = 0.f;
    for (int ky = 0; ky < 3; ++ky) {
      int rm = (a == 0) ? (ky == 0 ? 0 : 1) : (ky == 2 ? 1 : 0);
      if (rm != dy) continue;
      for (int kx = 0; kx < 3; ++kx) {
        int cm = (b2 == 0) ? (kx == 0 ? 0 : 1) : (kx == 2 ? 1 : 0);
        if (cm == dx) s += wsrc[ky * 3 + kx];
      }
    }
    fwd2[j] = s;
  }
}

// ---------------- Kernel A: conv1 (1->16) + maxpool2 + gelu --------------------
// Weights via wave-uniform scalar loads (no LDS, no sync).
__global__ __launch_bounds__(256) void k_enc1(const float* __restrict__ x,
                                              const float* __restrict__ w,
                                              const float* __restrict__ bias,
                                              float* __restrict__ h1) {
  int gid = blockIdx.x * 256 + threadIdx.x;
  int xx = gid & 127, yy = (gid >> 7) & 127, b = gid >> 14;
  const float* xp = x + (size_t)b * 65536;
  int r0 = 2 * yy - 1, c0 = 2 * xx - 1;
  float in[4][4];
#pragma unroll
  for (int i = 0; i < 4; ++i) {
    int r = r0 + i;
    bool rv = (unsigned)r < 256u;
#pragma unroll
    for (int j = 0; j < 4; ++j) {
      int c = c0 + j;
      in[i][j] = (rv && (unsigned)c < 256u) ? xp[r * 256 + c] : 0.0f;
    }
  }
  float* op = h1 + (size_t)b * 262144 + yy * 128 + xx;
#pragma unroll
  for (int oc = 0; oc < 16; ++oc) {
    const float* wp = w + oc * 9;  // uniform -> s_load
    float s00 = 0.f, s01 = 0.f, s10 = 0.f, s11 = 0.f;
#pragma unroll
    for (int ky = 0; ky < 3; ++ky)
#pragma unroll
      for (int kx = 0; kx < 3; ++kx) {
        float wv = wp[ky * 3 + kx];
        s00 = fmaf(in[ky][kx], wv, s00);
        s01 = fmaf(in[ky][kx + 1], wv, s01);
        s10 = fmaf(in[ky + 1][kx], wv, s10);
        s11 = fmaf(in[ky + 1][kx + 1], wv, s11);
      }
    float m = fmaxf(fmaxf(s00, s01), fmaxf(s10, s11)) + bias[oc];
    op[oc * 16384] = GELU(m);
  }
}

// ---------------- Kernel B: conv2 (16->32) + maxpool2 --------------------------
// Block: pooled 8x8 tile, 4 waves = 4 oc-groups (all 32 oc). Column-parity-split
// LDS tile (stride 20/row) makes even-strided pre-pool reads conflict-free
// (bank span 8*ty+tx: exact 2-way). Weights via SGPR (fwe2, scalar loads).
__global__ __launch_bounds__(256) void k_enc2(const float* __restrict__ h1,
                                              const float* __restrict__ fwe2,
                                              const float* __restrict__ bias,
                                              float* __restrict__ h2) {
  __shared__ float st[16 * 360];  // [ic][18 rows][20: evens 0-9, odds 10-19]
  int tid = threadIdx.x;
  int b = blockIdx.y;
  int Y0 = (blockIdx.x >> 3) * 8, X0 = (blockIdx.x & 7) * 8;
  int r_s = 2 * Y0 - 1, c_s = 2 * X0 - 1;
  const float* ip = h1 + (size_t)b * 262144;
  for (int i = tid; i < 5184; i += 256) {  // 16 ic x 18 x 18
    int ic = i / 324, rr = (i % 324) / 18, cc = i % 18;
    int r = r_s + rr, c = c_s + cc;
    float v = ((unsigned)r < 128u && (unsigned)c < 128u) ? ip[ic * 16384 + r * 128 + c] : 0.f;
    st[ic * 360 + rr * 20 + (cc & 1) * 10 + (cc >> 1)] = v;
  }
  __syncthreads();
  int lane = tid & 63;
  int grp = __builtin_amdgcn_readfirstlane(tid >> 6);
  int oc0 = grp * 8;
  int ty = lane >> 3, tx = lane & 7;
  float acc[4][8];
#pragma unroll
  for (int p = 0; p < 4; ++p)
#pragma unroll
    for (int o = 0; o < 8; ++o) acc[p][o] = 0.f;
  const float* wgrp = fwe2 + grp * 1152;  // scalar base
#pragma unroll 1
  for (int ic = 0; ic < 16; ++ic) {
    const float* t = st + ic * 360 + (2 * ty) * 20 + tx;
    float iv[4][4];
#pragma unroll
    for (int dy = 0; dy < 4; ++dy)
#pragma unroll
      for (int dx = 0; dx < 4; ++dx)
        iv[dy][dx] = t[dy * 20 + (dx & 1) * 10 + (dx >> 1)];
    const float* wp = wgrp + ic * 72;  // 72 floats, scalar loads
#pragma unroll
    for (int k = 0; k < 9; ++k) {
      int ky = k / 3, kx = k % 3;
#pragma unroll
      for (int o = 0; o < 8; ++o) {
        float wv = wp[k * 8 + o];
        acc[0][o] = fmaf(iv[ky][kx], wv, acc[0][o]);
        acc[1][o] = fmaf(iv[ky][kx + 1], wv, acc[1][o]);
        acc[2][o] = fmaf(iv[ky + 1][kx], wv, acc[2][o]);
        acc[3][o] = fmaf(iv[ky + 1][kx + 1], wv, acc[3][o]);
      }
    }
  }
  float* op = h2 + (size_t)b * 131072 + (Y0 + ty) * 64 + X0 + tx;
#pragma unroll
  for (int o = 0; o < 8; ++o) {
    float m = fmaxf(fmaxf(acc[0][o], acc[1][o]), fmaxf(acc[2][o], acc[3][o])) + bias[oc0 + o];
    op[(oc0 + o) * 4096] = m;
  }
}

// ---------------- Kernel C1: VQ distance scan over a 128-code chunk ------------
__global__ __launch_bounds__(256) void k_vq_chunk(const float* __restrict__ h2,
                                                  const float* __restrict__ cb,
                                                  float* __restrict__ dists,
                                                  int* __restrict__ idxs) {
  __shared__ float scsq[128];
  int tid = threadIdx.x;
  int chunk = blockIdx.x >> 8;
  int jbase = chunk << 7;
  if (tid < 128) {
    const float* row = cb + (size_t)(jbase + tid) * 32;
    float s = 0.f;
#pragma unroll
    for (int d = 0; d < 32; ++d) s = fmaf(row[d], row[d], s);
    scsq[tid] = s;
  }
  __syncthreads();
  int gid = (blockIdx.x & 255) * 256 + tid;
  int t0 = gid, t1 = gid + 65536;
  size_t a0 = (size_t)(t0 >> 12) * 131072 + (t0 & 4095);
  size_t a1 = (size_t)(t1 >> 12) * 131072 + (t1 & 4095);
  float f0[32], f1[32];
#pragma unroll
  for (int c = 0; c < 32; ++c) {
    f0[c] = h2[a0 + c * 4096];
    f1[c] = h2[a1 + c * 4096];
  }
  float best0 = 3.4e38f, best1 = 3.4e38f;
  int bi0 = jbase, bi1 = jbase;
  const float4* r4 = (const float4*)(cb + (size_t)jbase * 32);
#pragma unroll 1
  for (int jl = 0; jl < 128; ++jl) {
    const float4* row = r4 + (jl << 3);
    float a0s = 0.f, b0s = 0.f, a1s = 0.f, b1s = 0.f;
#pragma unroll
    for (int q = 0; q < 8; q += 2) {
      float4 v = row[q], u = row[q + 1];
      a0s = fmaf(v.x, f0[4*q+0], a0s); a0s = fmaf(v.y, f0[4*q+1], a0s);
      a0s = fmaf(v.z, f0[4*q+2], a0s); a0s = fmaf(v.w, f0[4*q+3], a0s);
      b0s = fmaf(u.x, f0[4*q+4], b0s); b0s = fmaf(u.y, f0[4*q+5], b0s);
      b0s = fmaf(u.z, f0[4*q+6], b0s); b0s = fmaf(u.w, f0[4*q+7], b0s);
      a1s = fmaf(v.x, f1[4*q+0], a1s); a1s = fmaf(v.y, f1[4*q+1], a1s);
      a1s = fmaf(v.z, f1[4*q+2], a1s); a1s = fmaf(v.w, f1[4*q+3], a1s);
      b1s = fmaf(u.x, f1[4*q+4], b1s); b1s = fmaf(u.y, f1[4*q+5], b1s);
      b1s = fmaf(u.z, f1[4*q+6], b1s); b1s = fmaf(u.w, f1[4*q+7], b1s);
    }
    float csq = scsq[jl];
    float d0 = csq - 2.0f * (a0s + b0s);
    float d1 = csq - 2.0f * (a1s + b1s);
    if (d0 < best0) { best0 = d0; bi0 = jbase + jl; }
    if (d1 < best1) { best1 = d1; bi1 = jbase + jl; }
  }
  size_t cbase = (size_t)chunk * 131072;
  dists[cbase + t0] = best0;
  dists[cbase + t1] = best1;
  idxs[cbase + t0] = bi0;
  idxs[cbase + t1] = bi1;
}

// ---------------- Kernel C2: merge 4 chunk candidates, quantize, loss ----------
__global__ __launch_bounds__(256) void k_vq_merge(float* __restrict__ h2,
                                                  const float* __restrict__ cb,
                                                  const float* __restrict__ dists,
                                                  const int* __restrict__ idxs,
                                                  float* __restrict__ idxout,
                                                  float* __restrict__ partial) {
  __shared__ float sred[4];
  int tid = threadIdx.x;
  int t = blockIdx.x * 256 + tid;
  float bd = dists[t];
  int bi = idxs[t];
#pragma unroll
  for (int k = 1; k < 4; ++k) {
    float dk = dists[(size_t)k * 131072 + t];
    int ik = idxs[(size_t)k * 131072 + t];
    if (dk < bd) { bd = dk; bi = ik; }
  }
  size_t a = (size_t)(t >> 12) * 131072 + (t & 4095);
  const float* q = cb + (size_t)bi * 32;
  float loss = 0.f;
#pragma unroll
  for (int c = 0; c < 32; ++c) {
    float f = h2[a + c * 4096];
    float qv = q[c];
    h2[a + c * 4096] = qv;
    float dd = qv - f;
    loss = fmaf(dd, dd, loss);
  }
  idxout[t] = (float)bi;
#pragma unroll
  for (int off = 32; off > 0; off >>= 1) loss += __shfl_down(loss, off, 64);
  if ((tid & 63) == 0) sred[tid >> 6] = loss;
  __syncthreads();
  if (tid == 0) partial[blockIdx.x] = (sred[0] + sred[1]) + (sred[2] + sred[3]);
}

// ---------------- Kernel F: finalize commit loss (512 partials) ----------------
__global__ __launch_bounds__(256) void k_loss(const float* __restrict__ partial,
                                              float* __restrict__ lossout) {
  __shared__ float sred[4];
  int tid = threadIdx.x;
  float v = partial[tid] + partial[tid + 256];
#pragma unroll
  for (int off = 32; off > 0; off >>= 1) v += __shfl_down(v, off, 64);
  if ((tid & 63) == 0) sred[tid >> 6] = v;
  __syncthreads();
  if (tid == 0)
    lossout[0] = ((sred[0] + sred[1]) + (sred[2] + sred[3])) * (1.0f / 4194304.0f);
}

// ---------------- Kernel D: up2 + conv (32->16) + gelu, phase-folded -----------
// Block: q-tile 8 rows x 16 cols (output 16x32). 4 waves: (qx half) x (oc grp).
// Per thread: one q-pos, 4 phases x 8 oc; 4 folded taps. LDS stride 20: bank
// spans 20*ty%32 = {0,20,8,28,16,4,24,12} -> exact 2-way (free).
__global__ __launch_bounds__(256) void k_dec1(const float* __restrict__ q,
                                              const float* __restrict__ fwd1,
                                              const float* __restrict__ bias,
                                              float* __restrict__ o) {
  __shared__ float st[32 * 200];  // [ic][10 rows][20]
  int tid = threadIdx.x;
  int b = blockIdx.y;
  int R0 = (blockIdx.x >> 2) * 8, C0 = (blockIdx.x & 3) * 16;
  const float* ip = q + (size_t)b * 131072;
  for (int i = tid; i < 5760; i += 256) {  // 32 ic x 10 x 18
    int ic = i / 180, rr = (i % 180) / 18, cc = i % 18;
    int r = R0 - 1 + rr, c = C0 - 1 + cc;
    st[ic * 200 + rr * 20 + cc] =
        ((unsigned)r < 64u && (unsigned)c < 64u) ? ip[ic * 4096 + r * 64 + c] : 0.f;
  }
  __syncthreads();
  int lane = tid & 63, wid = tid >> 6;
  int qx = wid & 1;
  int grp = __builtin_amdgcn_readfirstlane(wid >> 1);
  int ty = lane >> 3, tx = qx * 8 + (lane & 7);
  float acc[4][8];
#pragma unroll
  for (int p = 0; p < 4; ++p)
#pragma unroll
    for (int o2 = 0; o2 < 8; ++o2) acc[p][o2] = 0.f;
  const float* wb = fwd1 + grp * 4096;
#pragma unroll 1
  for (int ic = 0; ic < 32; ++ic) {
    const float* t = st + ic * 200 + ty * 20 + tx;
    float i3[3][3];
#pragma unroll
    for (int dy = 0; dy < 3; ++dy)
#pragma unroll
      for (int dx = 0; dx < 3; ++dx) i3[dy][dx] = t[dy * 20 + dx];
    const float* wp = wb + ic * 128;  // scalar loads
#pragma unroll
    for (int p = 0; p < 4; ++p) {
      int a = p >> 1, b2 = p & 1;
#pragma unroll
      for (int tp = 0; tp < 4; ++tp) {
        int dy = tp >> 1, dx = tp & 1;
        float iv = i3[a + dy][b2 + dx];
#pragma unroll
        for (int o2 = 0; o2 < 8; ++o2)
          acc[p][o2] = fmaf(iv, wp[(p * 4 + tp) * 8 + o2], acc[p][o2]);
      }
    }
  }
  int Y = 2 * (R0 + ty), X = 2 * (C0 + tx);
#pragma unroll
  for (int o2 = 0; o2 < 8; ++o2) {
    int oc = grp * 8 + o2;
    float bb = bias[oc];
    float* p = o + (size_t)b * 262144 + (size_t)oc * 16384 + Y * 128 + X;
    float2 r0v, r1v;
    r0v.x = GELU(acc[0][o2] + bb);
    r0v.y = GELU(acc[1][o2] + bb);
    r1v.x = GELU(acc[2][o2] + bb);
    r1v.y = GELU(acc[3][o2] + bb);
    *(float2*)p = r0v;
    *(float2*)(p + 128) = r1v;
  }
}

// ---------------- Kernel E: up2 + conv (16->1) + clip, phase-folded ------------
// Block: d1-tile 16x16 (output 32x32); 4 waves = 2x2 quadrants of 8x8 lanes.
__global__ __launch_bounds__(256) void k_dec2(const float* __restrict__ d1,
                                              const float* __restrict__ fwd2,
                                              const float* __restrict__ bias,
                                              float* __restrict__ out) {
  __shared__ float st[16 * 360];  // [ic][18 rows][20]
  int tid = threadIdx.x;
  int b = blockIdx.y;
  int R0 = (blockIdx.x >> 3) * 16, C0 = (blockIdx.x & 7) * 16;
  const float* ip = d1 + (size_t)b * 262144;
  for (int i = tid; i < 5184; i += 256) {  // 16 ic x 18 x 18
    int ic = i / 324, rr = (i % 324) / 18, cc = i % 18;
    int r = R0 - 1 + rr, c = C0 - 1 + cc;
    st[ic * 360 + rr * 20 + cc] =
        ((unsigned)r < 128u && (unsigned)c < 128u) ? ip[ic * 16384 + r * 128 + c] : 0.f;
  }
  __syncthreads();
  int lane = tid & 63, wid = tid >> 6;
  int qy = wid >> 1, qx = wid & 1;
  int ty = qy * 8 + (lane >> 3), tx = qx * 8 + (lane & 7);
  float acc[4] = {0.f, 0.f, 0.f, 0.f};
#pragma unroll 1
  for (int ic = 0; ic < 16; ++ic) {
    const float* t = st + ic * 360 + ty * 20 + tx;
    float i3[3][3];
#pragma unroll
    for (int dy = 0; dy < 3; ++dy)
#pragma unroll
      for (int dx = 0; dx < 3; ++dx) i3[dy][dx] = t[dy * 20 + dx];
    const float* wp = fwd2 + ic * 16;  // scalar loads
#pragma unroll
    for (int p = 0; p < 4; ++p) {
      int a = p >> 1, b2 = p & 1;
#pragma unroll
      for (int tp = 0; tp < 4; ++tp) {
        int dy = tp >> 1, dx = tp & 1;
        acc[p] = fmaf(i3[a + dy][b2 + dx], wp[p * 4 + tp], acc[p]);
      }
    }
  }
  float bv = bias[0];
  int Y = 2 * (R0 + ty), X = 2 * (C0 + tx);
  float* op = out + (size_t)b * 65536 + Y * 256 + X;
  float2 r0v, r1v;
  r0v.x = fminf(1.0f, fmaxf(-1.0f, acc[0] + bv));
  r0v.y = fminf(1.0f, fmaxf(-1.0f, acc[1] + bv));
  r1v.x = fminf(1.0f, fmaxf(-1.0f, acc[2] + bv));
  r1v.y = fminf(1.0f, fmaxf(-1.0f, acc[3] + bv));
  *(float2*)op = r0v;
  *(float2*)(op + 256) = r1v;
}

extern "C" void kernel_launch(void* const* d_in, const int* in_sizes, int n_in,
                              void* d_out, int out_size, void* d_ws, size_t ws_size,
                              hipStream_t stream) {
  const float* x   = (const float*)d_in[0];
  const float* e1w = (const float*)d_in[1];
  const float* e1b = (const float*)d_in[2];
  const float* e2w = (const float*)d_in[3];
  const float* e2b = (const float*)d_in[4];
  const float* cb  = (const float*)d_in[5];
  const float* d1w = (const float*)d_in[6];
  const float* d1b = (const float*)d_in[7];
  const float* d2w = (const float*)d_in[8];
  const float* d2b = (const float*)d_in[9];

  float* out = (float*)d_out;
  float* y       = out;                       // [32,1,256,256] = 2097152
  float* idxout  = out + 2097152;             // [32,64,64]     = 131072 (as float)
  float* lossout = out + 2097152 + 131072;    // scalar

  float* ws = (float*)d_ws;
  float* h1      = ws;                        // [32,16,128,128] = 8388608 floats
  float* h2      = ws + 8388608;              // [32,32,64,64]   = 4194304 floats
  float* partial = ws + 12582912;             // 512 floats
  float* fwe2    = ws + 12583424;             // 4608
  float* fwd1    = ws + 12588032;             // 8192
  float* fwd2    = ws + 12596224;             // 256
  // VQ chunk outputs reuse the (dead-after-enc2) h1 region:
  float* dists   = ws;                        // 4 x 131072 floats
  int*   idxs    = (int*)(ws + 524288);       // 4 x 131072 ints
  float* d1o     = h1;                        // dec1 output reuses h1 (after merge)

  k_fold<<<dim3(51), 256, 0, stream>>>(e2w, d1w, d2w, fwe2, fwd1, fwd2);
  k_enc1<<<dim3(2048), 256, 0, stream>>>(x, e1w, e1b, h1);
  k_enc2<<<dim3(64, 32), 256, 0, stream>>>(h1, fwe2, e2b, h2);
  k_vq_chunk<<<dim3(1024), 256, 0, stream>>>(h2, cb, dists, idxs);
  k_vq_merge<<<dim3(512), 256, 0, stream>>>(h2, cb, dists, idxs, idxout, partial);
  k_loss<<<dim3(1), 256, 0, stream>>>(partial, lossout);
  k_dec1<<<dim3(32, 32), 256, 0, stream>>>(h2, fwd1, d1b, d1o);
  k_dec2<<<dim3(64, 32), 256, 0, stream>>>(d1o, fwd2, d2b, y);
}